// Round 10
// baseline (117.316 us; speedup 1.0000x reference)
//
#include <hip/hip_runtime.h>
#include <math.h>

#define NH 49152
#define KI 1024
#define DD 32
#define HF 256
#define REPB 768

// float-index layout in ws
#define WS_PART  0                    // [0]=vrep [1]=vatt [2]=noise_sum [3]=n_noise(u32) [4]=sum(1-beta_a)
#define WS_SEG64 8                    // KI u64 packed (q_bits<<32 | NH-1-h)
#define WS_WT    2056                 // packed W: 4 octets x 2048 + 256 beta = 8448
#define WS_A12   (WS_WT + 8448)      // KI*12: d0..7, ca, qa, pad2
#define WS_H12   (WS_A12 + 12*KI)     // NH*12: d0..7, ch, q, bc, pad
#define WS_XA    (WS_H12 + 12*NH)     // KI*DD full alpha coords
#define WS_OX    (WS_XA + KI*DD)      // NH*DD

typedef __attribute__((address_space(1))) const unsigned int gu32;
typedef __attribute__((address_space(3))) unsigned int lu32;

__device__ __forceinline__ float rl(float v, int lane) {
    return __uint_as_float(__builtin_amdgcn_readlane(__float_as_uint(v), lane));
}

// pack W for per-wave VGPR residency:
// lane l, reg dk*8+col of octet w holds Wc[k= (l>>3)*32+(l&7)*4+dk ][w*8+col];
// beta: idx 8192 + l*4 + dk holds Wb[same k].
__global__ __launch_bounds__(256) void k_prep(const float* __restrict__ Wc,
                                              const float* __restrict__ Wb,
                                              float* __restrict__ ws) {
    const int i = blockIdx.x * 256 + threadIdx.x;
    if (i < 8192) {
        const int w = i >> 11, r2 = i & 2047;
        const int l = r2 >> 5, q = r2 & 31;
        const int dk = q >> 3, col = q & 7;
        const int k = (l >> 3) * 32 + (l & 7) * 4 + dk;
        ws[WS_WT + i] = Wc[(size_t)k * 32 + w * 8 + col];
    } else if (i < 8448) {
        const int r2 = i - 8192;
        const int l = r2 >> 2, dk = r2 & 3;
        const int k = (l >> 3) * 32 + (l & 7) * 4 + dk;
        ws[WS_WT + i] = Wb[k];
    }
    if (i < 512) *(float4*)(ws + WS_SEG64 + (size_t)i * 4) = make_float4(0.f, 0.f, 0.f, 0.f);
    if (i < 8) ws[WS_PART + i] = 0.0f;
}

// GEMM: W lives in VGPRs (one-time coalesced load), broadcast via v_readlane
// (pure VALU -> no LDS pipe, no scalar cache, no counter collisions).
// x staged async via global_load_lds, double-buffered, 1 barrier per 32-k chunk.
__global__ __launch_bounds__(256, 3) void k_gemm(
        const float* __restrict__ x, const float* __restrict__ bb,
        const float* __restrict__ bcrd, const int* __restrict__ yi,
        float* __restrict__ ws) {
    __shared__ float xs[2][8][256];   // [buf][window][lane*4]
    const int t0 = threadIdx.x;
    const int w  = __builtin_amdgcn_readfirstlane(t0 >> 6);  // col octet
    const int l  = t0 & 63;                                  // lane = hit
    const int h  = blockIdx.x * 64 + l;
    const float* __restrict__ wbase = ws + WS_WT + w * 2048;
    const float* __restrict__ xrow  = x + (size_t)h * HF;

    // one-time W preload into registers (8 coalesced dwordx4 per lane)
    float wr[32];
    #pragma unroll
    for (int q = 0; q < 8; ++q) {
        const float4 v = *(const float4*)(wbase + l * 32 + q * 4);
        wr[q * 4 + 0] = v.x; wr[q * 4 + 1] = v.y;
        wr[q * 4 + 2] = v.z; wr[q * 4 + 3] = v.w;
    }
    float br[4] = {0.f, 0.f, 0.f, 0.f};
    if (w == 3) {
        const float4 v = *(const float4*)(ws + WS_WT + 8192 + l * 4);
        br[0] = v.x; br[1] = v.y; br[2] = v.z; br[3] = v.w;
    }

    float acc[8];
    #pragma unroll
    for (int j = 0; j < 8; ++j) acc[j] = 0.0f;
    float accb = 0.0f;

    // async stage: wave w stages windows 2w, 2w+1 of chunk c1 into buf
#define STAGE(buf, c1) { \
    const float* s0 = xrow + (c1) * 32 + (2 * w) * 4; \
    __builtin_amdgcn_global_load_lds((gu32*)(const void*)s0, \
        (lu32*)(void*)&xs[buf][2 * w][0], 16, 0, 0); \
    const float* s1 = s0 + 4; \
    __builtin_amdgcn_global_load_lds((gu32*)(const void*)s1, \
        (lu32*)(void*)&xs[buf][2 * w + 1][0], 16, 0, 0); }

#define DK(dk, xc) { \
    acc[0] = fmaf(xc, rl(wr[(dk)*8 + 0], ls), acc[0]); \
    acc[1] = fmaf(xc, rl(wr[(dk)*8 + 1], ls), acc[1]); \
    acc[2] = fmaf(xc, rl(wr[(dk)*8 + 2], ls), acc[2]); \
    acc[3] = fmaf(xc, rl(wr[(dk)*8 + 3], ls), acc[3]); \
    acc[4] = fmaf(xc, rl(wr[(dk)*8 + 4], ls), acc[4]); \
    acc[5] = fmaf(xc, rl(wr[(dk)*8 + 5], ls), acc[5]); \
    acc[6] = fmaf(xc, rl(wr[(dk)*8 + 6], ls), acc[6]); \
    acc[7] = fmaf(xc, rl(wr[(dk)*8 + 7], ls), acc[7]); \
    if (w == 3) accb = fmaf(xc, rl(br[dk], ls), accb); }

    STAGE(0, 0);
    __syncthreads();                       // vmcnt(0)+lgkmcnt(0)+barrier
    for (int c = 0; c < 8; ++c) {
        if (c < 7) STAGE((c + 1) & 1, c + 1);   // in flight across compute
        const int lb = c * 8;              // uniform readlane base
        #pragma unroll
        for (int t = 0; t < 8; ++t) {
            const float4 xv = *(const float4*)&xs[c & 1][t][l * 4];
            const int ls = lb + t;
            DK(0, xv.x)
            DK(1, xv.y)
            DK(2, xv.z)
            DK(3, xv.w)
        }
        __syncthreads();                   // drains vmcnt -> next buf ready
    }

    // epilogue: lane owns hit h's col octet
    const float4 ba0 = *(const float4*)(bcrd + w * 8);
    const float4 ba1 = *(const float4*)(bcrd + w * 8 + 4);
    const float4 o0 = {acc[0] + ba0.x, acc[1] + ba0.y, acc[2] + ba0.z, acc[3] + ba0.w};
    const float4 o1 = {acc[4] + ba1.x, acc[5] + ba1.y, acc[6] + ba1.z, acc[7] + ba1.w};
    *(float4*)(ws + WS_OX + (size_t)h * DD + w * 8)     = o0;
    *(float4*)(ws + WS_OX + (size_t)h * DD + w * 8 + 4) = o1;

    if (w == 0) {   // cols 0..7: filter record dims + half-norm
        const float s8 = o0.x*o0.x + o0.y*o0.y + o0.z*o0.z + o0.w*o0.w
                       + o1.x*o1.x + o1.y*o1.y + o1.z*o1.z + o1.w*o1.w;
        float* hr = ws + WS_H12 + (size_t)h * 12;
        *(float4*)(hr)     = o0;
        *(float4*)(hr + 4) = o1;
        hr[8] = 0.5f * s8;
    }
    if (w == 3) {   // beta path + noise sums
        const float z    = accb + bb[0];
        const float beta = 1.0f / (1.0f + expf(-z));
        const float bcv  = fminf(fmaxf(beta, 1e-4f), 0.9999f);
        const float at   = atanhf(bcv);
        float* hr = ws + WS_H12 + (size_t)h * 12;
        hr[9]  = at * at + 0.5f;
        hr[10] = bcv;
        const int y = yi[h];
        float    nb  = (y < 0) ? bcv : 0.0f;
        unsigned cnt = (y < 0) ? 1u : 0u;
        for (int off = 32; off > 0; off >>= 1) {
            nb  += __shfl_down(nb, off);
            cnt += __shfl_down(cnt, off);
        }
        if (l == 0) {
            atomicAdd(ws + WS_PART + 2, nb);
            atomicAdd((unsigned int*)(ws + WS_PART + 3), cnt);
        }
    }
}

// fused segment argmax: pack (q_bits, NH-1-h) -> one u64 atomicMax.
__global__ __launch_bounds__(256) void k_segmax(const int* __restrict__ eh, const int* __restrict__ ei,
                                                int E, const float* __restrict__ h12,
                                                unsigned long long* __restrict__ seg) {
    int e = blockIdx.x * 256 + threadIdx.x;
    if (e < E) {
        int h = eh[e];
        float q = h12[(size_t)h * 12 + 9];
        unsigned long long pk = ((unsigned long long)__float_as_uint(q) << 32)
                              | (unsigned)(NH - 1 - h);
        atomicMax(seg + ei[e], pk);
    }
}

__global__ __launch_bounds__(256) void k_gather(float* __restrict__ ws) {
    const int k = blockIdx.x * 256 + threadIdx.x;
    unsigned long long pk = ((const unsigned long long*)(ws + WS_SEG64))[k];
    int a = NH - 1 - (int)(unsigned)(pk & 0xffffffffu);
    a = max(0, min(a, NH - 1));
    float4 v0, v1;
    float s8 = 0.0f;
    #pragma unroll
    for (int d0 = 0; d0 < DD; d0 += 4) {
        float4 v = *(const float4*)(ws + WS_OX + (size_t)a * DD + d0);
        *(float4*)(ws + WS_XA + (size_t)k * DD + d0) = v;
        if (d0 == 0) { v0 = v; s8 += v.x*v.x + v.y*v.y + v.z*v.z + v.w*v.w; }
        if (d0 == 4) { v1 = v; s8 += v.x*v.x + v.y*v.y + v.z*v.z + v.w*v.w; }
    }
    *(float4*)(ws + WS_A12 + (size_t)k * 12)     = v0;
    *(float4*)(ws + WS_A12 + (size_t)k * 12 + 4) = v1;
    ws[WS_A12 + (size_t)k * 12 + 8] = 0.5f * (s8 - 1.0f);                    // ca
    ws[WS_A12 + (size_t)k * 12 + 9] = ws[WS_H12 + (size_t)a * 12 + 9];       // qa
    float omba = 1.0f - ws[WS_H12 + (size_t)a * 12 + 10];
    for (int off = 32; off > 0; off >>= 1) omba += __shfl_down(omba, off);
    if ((threadIdx.x & 63) == 0) atomicAdd(ws + WS_PART + 4, omba);
}

// merged v_att + v_rep (single launch; blocks [0,REPB) = rep, rest = att)
__global__ __launch_bounds__(256, 4) void k_attrep(
        const int* __restrict__ eh, const int* __restrict__ ei, int E,
        const int* __restrict__ yi, float* __restrict__ ws) {
    __shared__ float al[128 * 12];
    __shared__ float red[4];
    const float* __restrict__ a12 = ws + WS_A12;
    const float* __restrict__ h12 = ws + WS_H12;
    const float* __restrict__ ox  = ws + WS_OX;
    const float* __restrict__ xa  = ws + WS_XA;
    const int t = threadIdx.x;

    if (blockIdx.x >= REPB) {
        // ---- attractive: one edge per thread ----
        const int e = (blockIdx.x - REPB) * 256 + t;
        float cv = 0.0f;
        if (e < E) {
            const int h = eh[e], k = ei[e];
            const float* a = ox + (size_t)h * DD;
            const float* b = xa + (size_t)k * DD;
            float d2 = 0.0f;
            #pragma unroll
            for (int d0 = 0; d0 < DD; d0 += 4) {
                float4 av = *(const float4*)(a + d0);
                float4 bv = *(const float4*)(b + d0);
                float dx = av.x - bv.x; d2 = fmaf(dx, dx, d2);
                float dy = av.y - bv.y; d2 = fmaf(dy, dy, d2);
                float dz = av.z - bv.z; d2 = fmaf(dz, dz, d2);
                float dw = av.w - bv.w; d2 = fmaf(dw, dw, d2);
            }
            cv = h12[(size_t)h * 12 + 9] * a12[(size_t)k * 12 + 9] * d2;
        }
        for (int off = 32; off > 0; off >>= 1) cv += __shfl_down(cv, off);
        if ((t & 63) == 0) red[t >> 6] = cv;
        __syncthreads();
        if (t == 0) atomicAdd(ws + WS_PART + 1, red[0] + red[1] + red[2] + red[3]);
        return;
    }

    // ---- repulsive: 512 hits x 128 alphas per block; exact 8-dim filter ----
    const int bh = blockIdx.x % 96;
    const int bk = blockIdx.x / 96;
    const int k0 = bk * 128;
    for (int i = t; i < 128 * 12; i += 256)
        al[i] = a12[(size_t)k0 * 12 + i];
    __syncthreads();

    const int h1 = bh * 512 + t;
    const int h2 = h1 + 256;
    const float4 p0  = *(const float4*)(h12 + (size_t)h1 * 12);
    const float4 p1  = *(const float4*)(h12 + (size_t)h1 * 12 + 4);
    const float2 cq1 = *(const float2*)(h12 + (size_t)h1 * 12 + 8);
    const float4 s0  = *(const float4*)(h12 + (size_t)h2 * 12);
    const float4 s1  = *(const float4*)(h12 + (size_t)h2 * 12 + 4);
    const float2 cq2 = *(const float2*)(h12 + (size_t)h2 * 12 + 8);
    const int yh1 = yi[h1], yh2 = yi[h2];
    float loc = 0.0f;

    #pragma unroll 4
    for (int r = 0; r < 128; ++r) {
        const float4 b0  = *(const float4*)(al + r * 12);
        const float4 b1  = *(const float4*)(al + r * 12 + 4);
        const float2 bcq = *(const float2*)(al + r * 12 + 8);
        float acc1 = -cq1.x - bcq.x;
        acc1 = fmaf(p0.x, b0.x, acc1);
        acc1 = fmaf(p0.y, b0.y, acc1);
        acc1 = fmaf(p0.z, b0.z, acc1);
        acc1 = fmaf(p0.w, b0.w, acc1);
        acc1 = fmaf(p1.x, b1.x, acc1);
        acc1 = fmaf(p1.y, b1.y, acc1);
        acc1 = fmaf(p1.z, b1.z, acc1);
        acc1 = fmaf(p1.w, b1.w, acc1);
        float acc2 = -cq2.x - bcq.x;
        acc2 = fmaf(s0.x, b0.x, acc2);
        acc2 = fmaf(s0.y, b0.y, acc2);
        acc2 = fmaf(s0.z, b0.z, acc2);
        acc2 = fmaf(s0.w, b0.w, acc2);
        acc2 = fmaf(s1.x, b1.x, acc2);
        acc2 = fmaf(s1.y, b1.y, acc2);
        acc2 = fmaf(s1.z, b1.z, acc2);
        acc2 = fmaf(s1.w, b1.w, acc2);
        if (acc1 > 0.0f) {          // rare: d2 over first 8 dims < 1
            const int kg = k0 + r;
            if (yh1 != kg) {
                float d2 = 1.0f - 2.0f * acc1;
                const float* hp  = ox + (size_t)h1 * DD;
                const float* apf = xa + (size_t)kg * DD;
                #pragma unroll
                for (int d = 8; d < DD; d += 4) {
                    float4 av = *(const float4*)(hp + d);
                    float4 bv = *(const float4*)(apf + d);
                    float dx = av.x - bv.x; d2 = fmaf(dx, dx, d2);
                    float dy = av.y - bv.y; d2 = fmaf(dy, dy, d2);
                    float dz = av.z - bv.z; d2 = fmaf(dz, dz, d2);
                    float dw = av.w - bv.w; d2 = fmaf(dw, dw, d2);
                }
                float dist = sqrtf(fmaxf(d2, 0.0f) + 1e-12f);
                float hin  = 1.0f - dist;
                if (hin > 0.0f) loc += cq1.y * bcq.y * hin;
            }
        }
        if (acc2 > 0.0f) {
            const int kg = k0 + r;
            if (yh2 != kg) {
                float d2 = 1.0f - 2.0f * acc2;
                const float* hp  = ox + (size_t)h2 * DD;
                const float* apf = xa + (size_t)kg * DD;
                #pragma unroll
                for (int d = 8; d < DD; d += 4) {
                    float4 av = *(const float4*)(hp + d);
                    float4 bv = *(const float4*)(apf + d);
                    float dx = av.x - bv.x; d2 = fmaf(dx, dx, d2);
                    float dy = av.y - bv.y; d2 = fmaf(dy, dy, d2);
                    float dz = av.z - bv.z; d2 = fmaf(dz, dz, d2);
                    float dw = av.w - bv.w; d2 = fmaf(dw, dw, d2);
                }
                float dist = sqrtf(fmaxf(d2, 0.0f) + 1e-12f);
                float hin  = 1.0f - dist;
                if (hin > 0.0f) loc += cq2.y * bcq.y * hin;
            }
        }
    }
    for (int off = 32; off > 0; off >>= 1) loc += __shfl_down(loc, off);
    if ((t & 63) == 0) red[t >> 6] = loc;
    __syncthreads();
    if (t == 0) atomicAdd(ws + WS_PART + 0, red[0] + red[1] + red[2] + red[3]);
}

__global__ void k_final(const float* __restrict__ temp, float* __restrict__ ws,
                        float* __restrict__ out) {
    float vrep  = ws[WS_PART + 0];
    float vatt  = ws[WS_PART + 1];
    float nsum  = ws[WS_PART + 2];
    unsigned nn = *(const unsigned int*)(ws + WS_PART + 3);
    float somba = ws[WS_PART + 4];
    float lb = somba * (1.0f / (float)KI) + nsum / (float)(nn < 1u ? 1u : nn);
    float lv = (vatt + vrep) / (float)NH;
    float tv = temp[0];
    out[0] = (lb + lv) * expf(-tv) + tv;
}

extern "C" void kernel_launch(void* const* d_in, const int* in_sizes, int n_in,
                              void* d_out, int out_size, void* d_ws, size_t ws_size,
                              hipStream_t stream) {
    const float* x    = (const float*)d_in[0];
    const float* Wb   = (const float*)d_in[1];
    const float* bb   = (const float*)d_in[2];
    const float* Wc   = (const float*)d_in[3];
    const float* bcrd = (const float*)d_in[4];
    const float* temp = (const float*)d_in[5];
    const int*   yi   = (const int*)d_in[6];
    const int*   ep   = (const int*)d_in[8];
    const int E = in_sizes[8] / 2;
    const int* eh = ep;
    const int* ei = ep + E;
    float* ws  = (float*)d_ws;
    float* out = (float*)d_out;

    k_prep<<<33, 256, 0, stream>>>(Wc, Wb, ws);
    k_gemm<<<NH / 64, 256, 0, stream>>>(x, bb, bcrd, yi, ws);
    const int eb = (E + 255) / 256;
    k_segmax<<<eb, 256, 0, stream>>>(eh, ei, E, ws + WS_H12,
                                     (unsigned long long*)(ws + WS_SEG64));
    k_gather<<<KI / 256, 256, 0, stream>>>(ws);
    k_attrep<<<REPB + eb, 256, 0, stream>>>(eh, ei, E, yi, ws);
    k_final<<<1, 1, 0, stream>>>(temp, ws, out);
}